// Round 4
// baseline (321.909 us; speedup 1.0000x reference)
//
#include <hip/hip_runtime.h>
#include <hip/hip_bf16.h>
#include <stdint.h>

#define E_EDGES 262144
#define DFEAT 256
#define KDIM 512
#define NNODES 131072

typedef __attribute__((ext_vector_type(8))) short short8;
typedef __attribute__((ext_vector_type(4))) float f32x4;

static __device__ __forceinline__ unsigned short f2bf(float x) {
    unsigned u = __float_as_uint(x);
    u += 0x7fffu + ((u >> 16) & 1u);   // RNE
    return (unsigned short)(u >> 16);
}

// table [131072][256] f32 -> bf16, same layout. 8 floats/thread.
__global__ __launch_bounds__(256) void conv_table_kernel(const float* __restrict__ t,
                                                         unsigned short* __restrict__ o) {
    int idx = blockIdx.x * 256 + threadIdx.x;
    float4 a = ((const float4*)t)[idx * 2];
    float4 b = ((const float4*)t)[idx * 2 + 1];
    uint4 w;
    w.x = (unsigned)f2bf(a.x) | ((unsigned)f2bf(a.y) << 16);
    w.y = (unsigned)f2bf(a.z) | ((unsigned)f2bf(a.w) << 16);
    w.z = (unsigned)f2bf(b.x) | ((unsigned)f2bf(b.y) << 16);
    w.w = (unsigned)f2bf(b.z) | ((unsigned)f2bf(b.w) << 16);
    ((uint4*)o)[idx] = w;
}

// W1 [512][256] f32 -> W1T [256][512] bf16
__global__ __launch_bounds__(256) void prep_w1t_kernel(const float* __restrict__ W1,
                                                       unsigned short* __restrict__ w1t) {
    int idx = blockIdx.x * 256 + threadIdx.x;
    int k = idx >> 8;
    int n = idx & 255;
    w1t[n * KDIM + k] = f2bf(W1[idx]);
}

// ============================ fast path ============================
// 64 edges x 256 cols per block. K=512 in 4 phases of 128.
// 3-buffer LDS pipeline, counted vmcnt (never 0 in steady state),
// B-loads issued BEFORE next-stage so their waitcnt doesn't drain the gather.
__global__ __launch_bounds__(256) void linkpred3_kernel(
    const unsigned short* __restrict__ tblb,
    const int* __restrict__ pos_src, const int* __restrict__ pos_dst,
    const int* __restrict__ neg_src, const int* __restrict__ neg_dst,
    const float* __restrict__ b1, const float* __restrict__ W2,
    const float* __restrict__ b2,
    const unsigned short* __restrict__ w1t,
    float* __restrict__ out) {

    __shared__ __align__(16) unsigned short As[3][64 * 128];  // 3 x 16 KB
    __shared__ float wpart[4][64];

    const int tid = threadIdx.x;
    const int l = tid & 63;
    const int wv = tid >> 6;
    const int m0 = blockIdx.x * 64;
    const bool is_pos = (m0 < E_EDGES);

    // per-lane gather indices for the 4 rows this lane stages (rows (wv*4+jj)*4 + (l>>4))
    int sIdxR[4], dIdxR[4];
#pragma unroll
    for (int jj = 0; jj < 4; ++jj) {
        int r = (wv * 4 + jj) * 4 + (l >> 4);
        int m = m0 + r;
        if (is_pos) { sIdxR[jj] = pos_src[m];            dIdxR[jj] = pos_dst[m]; }
        else        { int mm = m - E_EDGES; sIdxR[jj] = neg_src[mm]; dIdxR[jj] = neg_dst[mm]; }
    }

    float b1v[4], w2v[4];
#pragma unroll
    for (int j = 0; j < 4; j++) {
        int n = wv * 64 + j * 16 + (l & 15);
        b1v[j] = b1[n];
        w2v[j] = W2[n];
    }

    // stage phase s into As[buf]. LDS layout: row r (256B), 16 slots of 16B;
    // data chunk q stored at slot (q^r)&15 (involution). global_load_lds dest is
    // wave-uniform base + lane*16 (linear); the source address carries the swizzle.
    auto stage = [&](int buf, int s) {
        const int sel = s >> 1;          // 0: src node, 1: dst node
#pragma unroll
        for (int jj = 0; jj < 4; ++jj) {
            int j = wv * 4 + jj;
            int r = j * 4 + (l >> 4);
            int q = ((l & 15) ^ r) & 15;
            int idx = sel ? dIdxR[jj] : sIdxR[jj];
            const unsigned short* g = tblb + (size_t)idx * DFEAT + (s & 1) * 128 + q * 8;
            char* lp = (char*)(&As[buf][0]) + j * 1024;
            __builtin_amdgcn_global_load_lds(
                (const __attribute__((address_space(1))) void*)g,
                (__attribute__((address_space(3))) void*)lp, 16, 0, 0);
        }
    };

    stage(0, 0);
    stage(1, 1);

    f32x4 acc[4][4];
#pragma unroll
    for (int i = 0; i < 4; i++)
#pragma unroll
        for (int j = 0; j < 4; j++)
            acc[i][j] = (f32x4){0.f, 0.f, 0.f, 0.f};

    const unsigned short* bbase = w1t + (size_t)(wv * 64 + (l & 15)) * KDIM + ((l >> 4) << 3);

#pragma unroll
    for (int s = 0; s < 4; ++s) {
        // wait for THIS phase's tile only; keep younger stage loads in flight
        if (s < 3) asm volatile("s_waitcnt vmcnt(4)" ::: "memory");
        else       asm volatile("s_waitcnt vmcnt(0)" ::: "memory");
        __builtin_amdgcn_s_barrier();

        // B-fragments for this phase — issued BEFORE the next stage so the
        // compiler's wait-for-B cannot (in-order vmcnt) drain the gather.
        short8 bfr[4][4];
#pragma unroll
        for (int h = 0; h < 4; ++h)
#pragma unroll
            for (int j = 0; j < 4; ++j)
                bfr[h][j] = *(const short8*)(bbase + (size_t)j * 16 * KDIM + s * 128 + h * 32);

        if (s < 2) stage((s + 2) % 3, s + 2);   // FIX: buffer index is mod 3

        const char* Ab = (const char*)(&As[s % 3][0]);
        __builtin_amdgcn_s_setprio(1);
#pragma unroll
        for (int h = 0; h < 4; ++h) {
            int q = h * 4 + (l >> 4);
            int slot = (q ^ (l & 15)) & 15;   // row&15 == l&15 for all i
            short8 af[4];
#pragma unroll
            for (int i = 0; i < 4; ++i)
                af[i] = *(const short8*)(Ab + (i * 16 + (l & 15)) * 256 + slot * 16);
#pragma unroll
            for (int i = 0; i < 4; ++i)
#pragma unroll
                for (int j = 0; j < 4; ++j)
                    acc[i][j] = __builtin_amdgcn_mfma_f32_16x16x32_bf16(af[i], bfr[h][j], acc[i][j], 0, 0, 0);
        }
        __builtin_amdgcn_s_setprio(0);
    }

    // fused epilogue: relu(acc + b1) dot W2 -> sigmoid; labels.
    float part[16];
#pragma unroll
    for (int i = 0; i < 4; i++) {
#pragma unroll
        for (int r = 0; r < 4; r++) {
            float p = 0.f;
#pragma unroll
            for (int j = 0; j < 4; j++) {
                float hv = acc[i][j][r] + b1v[j];
                hv = fmaxf(hv, 0.f);
                p = fmaf(hv, w2v[j], p);
            }
#pragma unroll
            for (int mk = 1; mk < 16; mk <<= 1) p += __shfl_xor(p, mk, 64);
            part[i * 4 + r] = p;
        }
    }
    __syncthreads();
    if ((l & 15) == 0) {
        int g = l >> 4;
#pragma unroll
        for (int i = 0; i < 4; i++)
#pragma unroll
            for (int r = 0; r < 4; r++)
                wpart[wv][i * 16 + g * 4 + r] = part[i * 4 + r];
    }
    __syncthreads();

    if (tid < 64) {
        float x = wpart[0][tid] + wpart[1][tid] + wpart[2][tid] + wpart[3][tid] + b2[0];
        float sg = 1.0f / (1.0f + __expf(-x));
        out[(size_t)m0 + tid] = sg;
        out[(size_t)(2 * E_EDGES) + m0 + tid] = is_pos ? 1.0f : 0.0f;
    }
}

// ============================ fallback (round-1, known-good) ============================
__global__ __launch_bounds__(256) void linkpred_fb_kernel(
    const float* __restrict__ table,
    const int* __restrict__ pos_src, const int* __restrict__ pos_dst,
    const int* __restrict__ neg_src, const int* __restrict__ neg_dst,
    const float* __restrict__ b1, const float* __restrict__ W2,
    const float* __restrict__ b2,
    const unsigned short* __restrict__ w1t,
    float* __restrict__ out) {

    __shared__ __align__(16) unsigned short As[2][64 * 64];
    __shared__ int sIdx[64], dIdx[64];
    __shared__ float wpart[4][64];

    const int tid = threadIdx.x;
    const int l = tid & 63;
    const int wv = tid >> 6;
    const int m0 = blockIdx.x * 64;

    if (tid < 64) {
        int m = m0 + tid;
        int si, di;
        if (m < E_EDGES) { si = pos_src[m];            di = pos_dst[m]; }
        else             { si = neg_src[m - E_EDGES];  di = neg_dst[m - E_EDGES]; }
        sIdx[tid] = si;
        dIdx[tid] = di;
    }

    float b1v[4], w2v[4];
#pragma unroll
    for (int j = 0; j < 4; j++) {
        int n = wv * 64 + j * 16 + (l & 15);
        b1v[j] = b1[n];
        w2v[j] = W2[n];
    }

    __syncthreads();

    const int e0 = tid >> 3;
    const int q  = tid & 7;
    const int e1 = e0 + 32;

    auto pack_write = [&](int buf, int e, const float4& x, const float4& y) {
        uint4 w;
        w.x = (unsigned)f2bf(x.x) | ((unsigned)f2bf(x.y) << 16);
        w.y = (unsigned)f2bf(x.z) | ((unsigned)f2bf(x.w) << 16);
        w.z = (unsigned)f2bf(y.x) | ((unsigned)f2bf(y.y) << 16);
        w.w = (unsigned)f2bf(y.z) | ((unsigned)f2bf(y.w) << 16);
        int byte = e * 128 + q * 16;
        byte ^= (e & 7) << 4;
        *(uint4*)((char*)(&As[buf][0]) + byte) = w;
    };

    {
        const float* p0 = table + (size_t)sIdx[e0] * DFEAT + q * 8;
        const float* p1 = table + (size_t)sIdx[e1] * DFEAT + q * 8;
        float4 a0 = *(const float4*)p0, a1 = *(const float4*)(p0 + 4);
        float4 c0 = *(const float4*)p1, c1 = *(const float4*)(p1 + 4);
        pack_write(0, e0, a0, a1);
        pack_write(0, e1, c0, c1);
    }
    __syncthreads();

    f32x4 acc[4][4];
#pragma unroll
    for (int i = 0; i < 4; i++)
#pragma unroll
        for (int j = 0; j < 4; j++)
            acc[i][j] = (f32x4){0.f, 0.f, 0.f, 0.f};

    for (int s = 0; s < 8; s++) {
        float4 a0, a1, c0, c1;
        if (s < 7) {
            int sn = s + 1;
            const int* idxA = (sn < 4) ? sIdx : dIdx;
            int cb = (sn & 3) * 64 + q * 8;
            const float* p0 = table + (size_t)idxA[e0] * DFEAT + cb;
            const float* p1 = table + (size_t)idxA[e1] * DFEAT + cb;
            a0 = *(const float4*)p0; a1 = *(const float4*)(p0 + 4);
            c0 = *(const float4*)p1; c1 = *(const float4*)(p1 + 4);
        }

        const int cur = s & 1;
        const char* Abase = (const char*)(&As[cur][0]);
#pragma unroll
        for (int h = 0; h < 2; h++) {
            short8 af[4], bf[4];
#pragma unroll
            for (int i = 0; i < 4; i++) {
                int row = i * 16 + (l & 15);
                int byte = row * 128 + h * 64 + ((l >> 4) << 4);
                byte ^= (l & 7) << 4;
                af[i] = *(const short8*)(Abase + byte);
            }
#pragma unroll
            for (int j = 0; j < 4; j++) {
                int col = wv * 64 + j * 16 + (l & 15);
                int koff = s * 64 + h * 32 + ((l >> 4) << 3);
                bf[j] = *(const short8*)(w1t + col * KDIM + koff);
            }
#pragma unroll
            for (int i = 0; i < 4; i++)
#pragma unroll
                for (int j = 0; j < 4; j++)
                    acc[i][j] = __builtin_amdgcn_mfma_f32_16x16x32_bf16(af[i], bf[j], acc[i][j], 0, 0, 0);
        }

        if (s < 7) {
            pack_write((s + 1) & 1, e0, a0, a1);
            pack_write((s + 1) & 1, e1, c0, c1);
        }
        __syncthreads();
    }

    float part[16];
#pragma unroll
    for (int i = 0; i < 4; i++) {
#pragma unroll
        for (int r = 0; r < 4; r++) {
            float p = 0.f;
#pragma unroll
            for (int j = 0; j < 4; j++) {
                float hv = acc[i][j][r] + b1v[j];
                hv = fmaxf(hv, 0.f);
                p = fmaf(hv, w2v[j], p);
            }
#pragma unroll
            for (int mk = 1; mk < 16; mk <<= 1) p += __shfl_xor(p, mk, 64);
            part[i * 4 + r] = p;
        }
    }
    if ((l & 15) == 0) {
        int g = l >> 4;
#pragma unroll
        for (int i = 0; i < 4; i++)
#pragma unroll
            for (int r = 0; r < 4; r++)
                wpart[wv][i * 16 + g * 4 + r] = part[i * 4 + r];
    }
    __syncthreads();

    if (tid < 64) {
        float x = wpart[0][tid] + wpart[1][tid] + wpart[2][tid] + wpart[3][tid] + b2[0];
        float sg = 1.0f / (1.0f + __expf(-x));
        out[(size_t)m0 + tid] = sg;
        out[(size_t)(2 * E_EDGES) + m0 + tid] = (m0 < E_EDGES) ? 1.0f : 0.0f;
    }
}

extern "C" void kernel_launch(void* const* d_in, const int* in_sizes, int n_in,
                              void* d_out, int out_size, void* d_ws, size_t ws_size,
                              hipStream_t stream) {
    const float* table = (const float*)d_in[0];
    const int* ps = (const int*)d_in[1];
    const int* pd = (const int*)d_in[2];
    const int* ns = (const int*)d_in[3];
    const int* nd = (const int*)d_in[4];
    const float* W1 = (const float*)d_in[5];
    const float* b1 = (const float*)d_in[6];
    const float* W2 = (const float*)d_in[7];
    const float* b2 = (const float*)d_in[8];
    float* out = (float*)d_out;

    const size_t tbl_bytes = (size_t)NNODES * DFEAT * 2;       // 67,108,864
    const size_t w1t_bytes = (size_t)256 * KDIM * 2;           // 262,144

    if (ws_size >= tbl_bytes + w1t_bytes) {
        unsigned short* tblb = (unsigned short*)d_ws;
        unsigned short* w1t = (unsigned short*)((char*)d_ws + tbl_bytes);
        hipLaunchKernelGGL(conv_table_kernel, dim3(16384), dim3(256), 0, stream, table, tblb);
        hipLaunchKernelGGL(prep_w1t_kernel, dim3(512), dim3(256), 0, stream, W1, w1t);
        hipLaunchKernelGGL(linkpred3_kernel, dim3(8192), dim3(256), 0, stream,
                           tblb, ps, pd, ns, nd, b1, W2, b2, w1t, out);
    } else {
        unsigned short* w1t = (unsigned short*)d_ws;
        hipLaunchKernelGGL(prep_w1t_kernel, dim3(512), dim3(256), 0, stream, W1, w1t);
        hipLaunchKernelGGL(linkpred_fb_kernel, dim3(8192), dim3(256), 0, stream,
                           table, ps, pd, ns, nd, b1, W2, b2, w1t, out);
    }
}

// Round 5
// 275.648 us; speedup vs baseline: 1.1678x; 1.1678x over previous
//
#include <hip/hip_runtime.h>
#include <hip/hip_bf16.h>
#include <stdint.h>

#define E_EDGES 262144
#define DFEAT 256
#define KDIM 512
#define NNODES 131072

typedef __attribute__((ext_vector_type(8))) short short8;
typedef __attribute__((ext_vector_type(4))) float f32x4;

static __device__ __forceinline__ unsigned short f2bf(float x) {
    unsigned u = __float_as_uint(x);
    u += 0x7fffu + ((u >> 16) & 1u);   // RNE
    return (unsigned short)(u >> 16);
}

// table [131072][256] f32 -> bf16, same layout. 8 floats/thread.
__global__ __launch_bounds__(256) void conv_table_kernel(const float* __restrict__ t,
                                                         unsigned short* __restrict__ o) {
    int idx = blockIdx.x * 256 + threadIdx.x;
    float4 a = ((const float4*)t)[idx * 2];
    float4 b = ((const float4*)t)[idx * 2 + 1];
    uint4 w;
    w.x = (unsigned)f2bf(a.x) | ((unsigned)f2bf(a.y) << 16);
    w.y = (unsigned)f2bf(a.z) | ((unsigned)f2bf(a.w) << 16);
    w.z = (unsigned)f2bf(b.x) | ((unsigned)f2bf(b.y) << 16);
    w.w = (unsigned)f2bf(b.z) | ((unsigned)f2bf(b.w) << 16);
    ((uint4*)o)[idx] = w;
}

// W1 [512][256] f32 -> W1T [256][512] bf16
__global__ __launch_bounds__(256) void prep_w1t_kernel(const float* __restrict__ W1,
                                                       unsigned short* __restrict__ w1t) {
    int idx = blockIdx.x * 256 + threadIdx.x;
    int k = idx >> 8;
    int n = idx & 255;
    w1t[n * KDIM + k] = f2bf(W1[idx]);
}

// ============================ fast path (A-in-registers) ============================
// Block = 4 waves x 32 edges = 128 edges. Per lane: 32x16B A-fragment gathers,
// ALL issued in the prologue (deep MLP: ~512B/lane in flight -> gather is BW-bound,
// not latency-bound). B = W1T staged per 64-col chunk into 64KB LDS from L2.
__global__ __launch_bounds__(256) void linkpred4_kernel(
    const unsigned short* __restrict__ tblb,
    const int* __restrict__ pos_src, const int* __restrict__ pos_dst,
    const int* __restrict__ neg_src, const int* __restrict__ neg_dst,
    const float* __restrict__ b1, const float* __restrict__ W2,
    const float* __restrict__ b2,
    const unsigned short* __restrict__ w1t,
    float* __restrict__ out) {

    __shared__ __align__(16) unsigned short Bs[64 * 512];   // 64 KB, single buffer

    const int tid = threadIdx.x;
    const int l = tid & 63;
    const int wv = tid >> 6;
    const int l15 = l & 15;
    const int lq = l >> 4;
    const int m0 = blockIdx.x * 128;
    const bool is_pos = (m0 < E_EDGES);   // E = 2048 blocks of 128 -> block-uniform

    // node indices for this lane's 2 m-tiles (row = l15 within tile)
    int nsrc[2], ndst[2];
#pragma unroll
    for (int mt = 0; mt < 2; ++mt) {
        int m = m0 + wv * 32 + mt * 16 + l15;
        if (is_pos) { nsrc[mt] = pos_src[m];            ndst[mt] = pos_dst[m]; }
        else        { int mm = m - E_EDGES; nsrc[mt] = neg_src[mm]; ndst[mt] = neg_dst[mm]; }
    }

    // stage B col-chunk c: 64 cols x K512 bf16 = 64 KB. One 1KB instr per col.
    // Stored slot l holds data slot (l ^ (col&15)); col&15 == i, involution with read.
    auto stageB = [&](int c) {
#pragma unroll
        for (int i = 0; i < 16; ++i) {
            int lc = wv * 16 + i;
            int gc = c * 64 + lc;
            const unsigned short* g = w1t + (size_t)gc * KDIM + ((l ^ i) << 3);
            char* lp = (char*)Bs + lc * 1024;
            __builtin_amdgcn_global_load_lds(
                (const __attribute__((address_space(1))) void*)g,
                (__attribute__((address_space(3))) void*)lp, 16, 0, 0);
        }
    };

    // ---- B-stage chunk 0 FIRST (so vmcnt(32) below == "B done, A still flying") ----
    stageB(0);
    __builtin_amdgcn_sched_barrier(0);

    // ---- issue ALL 32 A-fragment gathers per lane ----
    // af[mt][h]: 16B at node row, feats (h&7)*32 + lq*8; h<8 = src, h>=8 = dst.
    short8 af[2][16];
#pragma unroll
    for (int h = 0; h < 16; ++h)
#pragma unroll
        for (int mt = 0; mt < 2; ++mt) {
            int node = (h < 8) ? nsrc[mt] : ndst[mt];
            const unsigned short* g = tblb + (size_t)node * DFEAT + (h & 7) * 32 + lq * 8;
            af[mt][h] = *(const short8*)g;
        }
    __builtin_amdgcn_sched_barrier(0);

    f32x4 acc[2][4];
#pragma unroll
    for (int mt = 0; mt < 2; ++mt)
#pragma unroll
        for (int j = 0; j < 4; ++j)
            acc[mt][j] = (f32x4){0.f, 0.f, 0.f, 0.f};
    float rowacc[2][4] = {{0.f, 0.f, 0.f, 0.f}, {0.f, 0.f, 0.f, 0.f}};

    const char* Bb = (const char*)Bs;

#pragma unroll
    for (int c = 0; c < 4; ++c) {
        if (c == 0) {
            // B(0) done when only the 32 A-loads remain outstanding
            asm volatile("s_waitcnt vmcnt(32)" ::: "memory");
        } else {
            __syncthreads();            // all waves done reading Bs for chunk c-1
            stageB(c);
            // fold chunk c-1 (register-only) while the L2 stage flies
#pragma unroll
            for (int mt = 0; mt < 2; ++mt)
#pragma unroll
                for (int j = 0; j < 4; ++j) {
                    int col = (c - 1) * 64 + j * 16 + l15;
                    float b1v = b1[col], w2v = W2[col];
#pragma unroll
                    for (int r = 0; r < 4; ++r) {
                        float hv = fmaxf(acc[mt][j][r] + b1v, 0.f);
                        rowacc[mt][r] = fmaf(hv, w2v, rowacc[mt][r]);
                    }
                    acc[mt][j] = (f32x4){0.f, 0.f, 0.f, 0.f};
                }
            asm volatile("s_waitcnt vmcnt(0)" ::: "memory");
        }
        __builtin_amdgcn_s_barrier();

        __builtin_amdgcn_s_setprio(1);
#pragma unroll
        for (int h = 0; h < 16; ++h) {
            short8 bf[4];
#pragma unroll
            for (int j = 0; j < 4; ++j) {
                int cl = j * 16 + l15;
                int phys = (h * 4 + lq) ^ l15;        // 2-way max on banks: free
                bf[j] = *(const short8*)(Bb + cl * 1024 + phys * 16);
            }
#pragma unroll
            for (int mt = 0; mt < 2; ++mt)
#pragma unroll
                for (int j = 0; j < 4; ++j)
                    acc[mt][j] = __builtin_amdgcn_mfma_f32_16x16x32_bf16(af[mt][h], bf[j], acc[mt][j], 0, 0, 0);
        }
        __builtin_amdgcn_s_setprio(0);
    }

    // fold last chunk
#pragma unroll
    for (int mt = 0; mt < 2; ++mt)
#pragma unroll
        for (int j = 0; j < 4; ++j) {
            int col = 3 * 64 + j * 16 + l15;
            float b1v = b1[col], w2v = W2[col];
#pragma unroll
            for (int r = 0; r < 4; ++r) {
                float hv = fmaxf(acc[mt][j][r] + b1v, 0.f);
                rowacc[mt][r] = fmaf(hv, w2v, rowacc[mt][r]);
            }
        }

    // reduce over the 16 col-lanes; lane l15==0 holds rows lq*4 + r of m-tile mt
    const float b2v = b2[0];
#pragma unroll
    for (int mt = 0; mt < 2; ++mt)
#pragma unroll
        for (int r = 0; r < 4; ++r) {
            float p = rowacc[mt][r];
#pragma unroll
            for (int mk = 1; mk < 16; mk <<= 1) p += __shfl_xor(p, mk, 64);
            if (l15 == 0) {
                int m = m0 + wv * 32 + mt * 16 + lq * 4 + r;
                float sg = 1.0f / (1.0f + __expf(-(p + b2v)));
                out[(size_t)m] = sg;
                out[(size_t)(2 * E_EDGES) + m] = is_pos ? 1.0f : 0.0f;
            }
        }
}

// ============================ fallback (round-1, known-good) ============================
__global__ __launch_bounds__(256) void linkpred_fb_kernel(
    const float* __restrict__ table,
    const int* __restrict__ pos_src, const int* __restrict__ pos_dst,
    const int* __restrict__ neg_src, const int* __restrict__ neg_dst,
    const float* __restrict__ b1, const float* __restrict__ W2,
    const float* __restrict__ b2,
    const unsigned short* __restrict__ w1t,
    float* __restrict__ out) {

    __shared__ __align__(16) unsigned short As[2][64 * 64];
    __shared__ int sIdx[64], dIdx[64];
    __shared__ float wpart[4][64];

    const int tid = threadIdx.x;
    const int l = tid & 63;
    const int wv = tid >> 6;
    const int m0 = blockIdx.x * 64;

    if (tid < 64) {
        int m = m0 + tid;
        int si, di;
        if (m < E_EDGES) { si = pos_src[m];            di = pos_dst[m]; }
        else             { si = neg_src[m - E_EDGES];  di = neg_dst[m - E_EDGES]; }
        sIdx[tid] = si;
        dIdx[tid] = di;
    }

    float b1v[4], w2v[4];
#pragma unroll
    for (int j = 0; j < 4; j++) {
        int n = wv * 64 + j * 16 + (l & 15);
        b1v[j] = b1[n];
        w2v[j] = W2[n];
    }

    __syncthreads();

    const int e0 = tid >> 3;
    const int q  = tid & 7;
    const int e1 = e0 + 32;

    auto pack_write = [&](int buf, int e, const float4& x, const float4& y) {
        uint4 w;
        w.x = (unsigned)f2bf(x.x) | ((unsigned)f2bf(x.y) << 16);
        w.y = (unsigned)f2bf(x.z) | ((unsigned)f2bf(x.w) << 16);
        w.z = (unsigned)f2bf(y.x) | ((unsigned)f2bf(y.y) << 16);
        w.w = (unsigned)f2bf(y.z) | ((unsigned)f2bf(y.w) << 16);
        int byte = e * 128 + q * 16;
        byte ^= (e & 7) << 4;
        *(uint4*)((char*)(&As[buf][0]) + byte) = w;
    };

    {
        const float* p0 = table + (size_t)sIdx[e0] * DFEAT + q * 8;
        const float* p1 = table + (size_t)sIdx[e1] * DFEAT + q * 8;
        float4 a0 = *(const float4*)p0, a1 = *(const float4*)(p0 + 4);
        float4 c0 = *(const float4*)p1, c1 = *(const float4*)(p1 + 4);
        pack_write(0, e0, a0, a1);
        pack_write(0, e1, c0, c1);
    }
    __syncthreads();

    f32x4 acc[4][4];
#pragma unroll
    for (int i = 0; i < 4; i++)
#pragma unroll
        for (int j = 0; j < 4; j++)
            acc[i][j] = (f32x4){0.f, 0.f, 0.f, 0.f};

    for (int s = 0; s < 8; s++) {
        float4 a0, a1, c0, c1;
        if (s < 7) {
            int sn = s + 1;
            const int* idxA = (sn < 4) ? sIdx : dIdx;
            int cb = (sn & 3) * 64 + q * 8;
            const float* p0 = table + (size_t)idxA[e0] * DFEAT + cb;
            const float* p1 = table + (size_t)idxA[e1] * DFEAT + cb;
            a0 = *(const float4*)p0; a1 = *(const float4*)(p0 + 4);
            c0 = *(const float4*)p1; c1 = *(const float4*)(p1 + 4);
        }

        const int cur = s & 1;
        const char* Abase = (const char*)(&As[cur][0]);
#pragma unroll
        for (int h = 0; h < 2; h++) {
            short8 af[4], bf[4];
#pragma unroll
            for (int i = 0; i < 4; i++) {
                int row = i * 16 + (l & 15);
                int byte = row * 128 + h * 64 + ((l >> 4) << 4);
                byte ^= (l & 7) << 4;
                af[i] = *(const short8*)(Abase + byte);
            }
#pragma unroll
            for (int j = 0; j < 4; j++) {
                int col = wv * 64 + j * 16 + (l & 15);
                int koff = s * 64 + h * 32 + ((l >> 4) << 3);
                bf[j] = *(const short8*)(w1t + col * KDIM + koff);
            }
#pragma unroll
            for (int i = 0; i < 4; i++)
#pragma unroll
                for (int j = 0; j < 4; j++)
                    acc[i][j] = __builtin_amdgcn_mfma_f32_16x16x32_bf16(af[i], bf[j], acc[i][j], 0, 0, 0);
        }

        if (s < 7) {
            pack_write((s + 1) & 1, e0, a0, a1);
            pack_write((s + 1) & 1, e1, c0, c1);
        }
        __syncthreads();
    }

    float part[16];
#pragma unroll
    for (int i = 0; i < 4; i++) {
#pragma unroll
        for (int r = 0; r < 4; r++) {
            float p = 0.f;
#pragma unroll
            for (int j = 0; j < 4; j++) {
                float hv = acc[i][j][r] + b1v[j];
                hv = fmaxf(hv, 0.f);
                p = fmaf(hv, w2v[j], p);
            }
#pragma unroll
            for (int mk = 1; mk < 16; mk <<= 1) p += __shfl_xor(p, mk, 64);
            part[i * 4 + r] = p;
        }
    }
    if ((l & 15) == 0) {
        int g = l >> 4;
#pragma unroll
        for (int i = 0; i < 4; i++)
#pragma unroll
            for (int r = 0; r < 4; r++)
                wpart[wv][i * 16 + g * 4 + r] = part[i * 4 + r];
    }
    __syncthreads();

    if (tid < 64) {
        float x = wpart[0][tid] + wpart[1][tid] + wpart[2][tid] + wpart[3][tid] + b2[0];
        float sg = 1.0f / (1.0f + __expf(-x));
        out[(size_t)m0 + tid] = sg;
        out[(size_t)(2 * E_EDGES) + m0 + tid] = (m0 < E_EDGES) ? 1.0f : 0.0f;
    }
}

extern "C" void kernel_launch(void* const* d_in, const int* in_sizes, int n_in,
                              void* d_out, int out_size, void* d_ws, size_t ws_size,
                              hipStream_t stream) {
    const float* table = (const float*)d_in[0];
    const int* ps = (const int*)d_in[1];
    const int* pd = (const int*)d_in[2];
    const int* ns = (const int*)d_in[3];
    const int* nd = (const int*)d_in[4];
    const float* W1 = (const float*)d_in[5];
    const float* b1 = (const float*)d_in[6];
    const float* W2 = (const float*)d_in[7];
    const float* b2 = (const float*)d_in[8];
    float* out = (float*)d_out;

    const size_t tbl_bytes = (size_t)NNODES * DFEAT * 2;       // 67,108,864
    const size_t w1t_bytes = (size_t)256 * KDIM * 2;           // 262,144

    if (ws_size >= tbl_bytes + w1t_bytes) {
        unsigned short* tblb = (unsigned short*)d_ws;
        unsigned short* w1t = (unsigned short*)((char*)d_ws + tbl_bytes);
        hipLaunchKernelGGL(conv_table_kernel, dim3(16384), dim3(256), 0, stream, table, tblb);
        hipLaunchKernelGGL(prep_w1t_kernel, dim3(512), dim3(256), 0, stream, W1, w1t);
        hipLaunchKernelGGL(linkpred4_kernel, dim3(4096), dim3(256), 0, stream,
                           tblb, ps, pd, ns, nd, b1, W2, b2, w1t, out);
    } else {
        unsigned short* w1t = (unsigned short*)d_ws;
        hipLaunchKernelGGL(prep_w1t_kernel, dim3(512), dim3(256), 0, stream, W1, w1t);
        hipLaunchKernelGGL(linkpred_fb_kernel, dim3(8192), dim3(256), 0, stream,
                           table, ps, pd, ns, nd, b1, W2, b2, w1t, out);
    }
}

// Round 6
// 186.979 us; speedup vs baseline: 1.7216x; 1.4742x over previous
//
#include <hip/hip_runtime.h>
#include <hip/hip_bf16.h>
#include <stdint.h>

#define E_EDGES 262144
#define DFEAT 256
#define KDIM 512
#define NNODES 131072

typedef __attribute__((ext_vector_type(8))) short short8;
typedef __attribute__((ext_vector_type(4))) float f32x4;

static __device__ __forceinline__ unsigned short f2bf(float x) {
    unsigned u = __float_as_uint(x);
    u += 0x7fffu + ((u >> 16) & 1u);   // RNE
    return (unsigned short)(u >> 16);
}
static __device__ __forceinline__ float bf2f(unsigned short s) {
    return __uint_as_float(((unsigned)s) << 16);
}

// ===================== new fast path =====================
// wB[n][k], n in [0,512) output col (u:0-255, v:256-511), k in [0,256) input feat.
// wB[n*256+k] = W1[k + 256*(n>=256)][n&255]
__global__ __launch_bounds__(256) void prep_wB_kernel(const float* __restrict__ W1,
                                                      unsigned short* __restrict__ wB) {
    int idx = blockIdx.x * 256 + threadIdx.x;   // 131072
    int n = idx >> 8;
    int k = idx & 255;
    int srow = k + ((n >= 256) ? 256 : 0);
    wB[idx] = f2bf(W1[srow * 256 + (n & 255)]);
}

// uv[node][512] bf16 = [x@W1a , x@W1b]. Dense streaming GEMM, no gathers.
// Block: 64 nodes x 512 cols, 4 waves (each 64M x 128N). K=256 one-shot in LDS.
__global__ __launch_bounds__(256) void gemm_uv_kernel(const float* __restrict__ table,
                                                      const unsigned short* __restrict__ wB,
                                                      unsigned short* __restrict__ uv) {
    __shared__ __align__(16) unsigned short As[64 * 256];   // 32 KB

    const int tid = threadIdx.x;
    const int l = tid & 63;
    const int wv = tid >> 6;
    const int l15 = l & 15;
    const int lq = l >> 4;
    const int m0 = blockIdx.x * 64;

    // reg-staged convert f32 -> bf16 into swizzled LDS tile [64 rows][32 granules]
    // phys granule = gc ^ (row & 15)  (involution with the read side)
#pragma unroll
    for (int r = 0; r < 8; ++r) {
        int lin = r * 256 + tid;
        int row = lin >> 5;
        int gc = lin & 31;
        const float* src = table + ((size_t)(m0 + row) * DFEAT + gc * 8);
        float4 a = *(const float4*)src;
        float4 b = *(const float4*)(src + 4);
        uint4 w;
        w.x = (unsigned)f2bf(a.x) | ((unsigned)f2bf(a.y) << 16);
        w.y = (unsigned)f2bf(a.z) | ((unsigned)f2bf(a.w) << 16);
        w.z = (unsigned)f2bf(b.x) | ((unsigned)f2bf(b.y) << 16);
        w.w = (unsigned)f2bf(b.z) | ((unsigned)f2bf(b.w) << 16);
        int phys = gc ^ (row & 15);
        *(uint4*)((char*)As + row * 512 + phys * 16) = w;
    }
    __syncthreads();

    f32x4 acc[4][8];
#pragma unroll
    for (int i = 0; i < 4; ++i)
#pragma unroll
        for (int j = 0; j < 8; ++j)
            acc[i][j] = (f32x4){0.f, 0.f, 0.f, 0.f};

#pragma unroll
    for (int kk = 0; kk < 8; ++kk) {
        short8 af[4];
#pragma unroll
        for (int i = 0; i < 4; ++i) {
            int row = i * 16 + l15;
            int phys = (kk * 4 + lq) ^ l15;     // row&15 == l15
            af[i] = *(const short8*)((char*)As + row * 512 + phys * 16);
        }
        short8 bf[8];
#pragma unroll
        for (int j = 0; j < 8; ++j) {
            int col = wv * 128 + j * 16 + l15;
            bf[j] = *(const short8*)(wB + (size_t)col * 256 + kk * 32 + lq * 8);
        }
#pragma unroll
        for (int i = 0; i < 4; ++i)
#pragma unroll
            for (int j = 0; j < 8; ++j)
                acc[i][j] = __builtin_amdgcn_mfma_f32_16x16x32_bf16(af[i], bf[j], acc[i][j], 0, 0, 0);
    }

    // C layout: col = l15, row = lq*4 + reg
#pragma unroll
    for (int i = 0; i < 4; ++i)
#pragma unroll
        for (int j = 0; j < 8; ++j) {
            int node = m0 + i * 16 + lq * 4;
            int col = wv * 128 + j * 16 + l15;
            unsigned short* p = uv + (size_t)node * 512 + col;
#pragma unroll
            for (int rr = 0; rr < 4; ++rr)
                p[(size_t)rr * 512] = f2bf(acc[i][j][rr]);
        }
}

// Edge pass: half-wave (32 lanes) per edge. Lane m handles z[8m..8m+8):
// z = u_src + v_dst + b1, p += relu(z)*W2; 5-step shfl reduce; sigmoid + label.
__global__ __launch_bounds__(256) void edge_kernel(
    const unsigned short* __restrict__ uv,
    const int* __restrict__ pos_src, const int* __restrict__ pos_dst,
    const int* __restrict__ neg_src, const int* __restrict__ neg_dst,
    const float* __restrict__ b1, const float* __restrict__ W2,
    const float* __restrict__ b2,
    float* __restrict__ out) {

    const int tid = threadIdx.x;
    const int m = tid & 31;
    const int hw = tid >> 5;
    const int e = blockIdx.x * 8 + hw;          // 65536 blocks x 8 = 2E
    const bool is_pos = (e < E_EDGES);          // E/8 = 32768 -> block-uniform
    const int ee = is_pos ? e : e - E_EDGES;
    const int src = is_pos ? pos_src[ee] : neg_src[ee];
    const int dst = is_pos ? pos_dst[ee] : neg_dst[ee];

    short8 uvec = *(const short8*)(uv + (size_t)src * 512 + m * 8);
    short8 vvec = *(const short8*)(uv + (size_t)dst * 512 + 256 + m * 8);

    float b1a[8], w2a[8];
    *(float4*)&b1a[0] = *(const float4*)(b1 + m * 8);
    *(float4*)&b1a[4] = *(const float4*)(b1 + m * 8 + 4);
    *(float4*)&w2a[0] = *(const float4*)(W2 + m * 8);
    *(float4*)&w2a[4] = *(const float4*)(W2 + m * 8 + 4);

    float p = 0.f;
#pragma unroll
    for (int i = 0; i < 8; ++i) {
        float z = bf2f((unsigned short)uvec[i]) + bf2f((unsigned short)vvec[i]) + b1a[i];
        z = fmaxf(z, 0.f);
        p = fmaf(z, w2a[i], p);
    }
#pragma unroll
    for (int mk = 1; mk < 32; mk <<= 1) p += __shfl_xor(p, mk, 64);

    if (m == 0) {
        float x = p + b2[0];
        out[(size_t)e] = 1.0f / (1.0f + __expf(-x));
        out[(size_t)(2 * E_EDGES) + e] = is_pos ? 1.0f : 0.0f;
    }
}

// ===================== mid-tier (round-5) =====================
__global__ __launch_bounds__(256) void conv_table_kernel(const float* __restrict__ t,
                                                         unsigned short* __restrict__ o) {
    int idx = blockIdx.x * 256 + threadIdx.x;
    float4 a = ((const float4*)t)[idx * 2];
    float4 b = ((const float4*)t)[idx * 2 + 1];
    uint4 w;
    w.x = (unsigned)f2bf(a.x) | ((unsigned)f2bf(a.y) << 16);
    w.y = (unsigned)f2bf(a.z) | ((unsigned)f2bf(a.w) << 16);
    w.z = (unsigned)f2bf(b.x) | ((unsigned)f2bf(b.y) << 16);
    w.w = (unsigned)f2bf(b.z) | ((unsigned)f2bf(b.w) << 16);
    ((uint4*)o)[idx] = w;
}

__global__ __launch_bounds__(256) void prep_w1t_kernel(const float* __restrict__ W1,
                                                       unsigned short* __restrict__ w1t) {
    int idx = blockIdx.x * 256 + threadIdx.x;
    int k = idx >> 8;
    int n = idx & 255;
    w1t[n * KDIM + k] = f2bf(W1[idx]);
}

__global__ __launch_bounds__(256) void linkpred4_kernel(
    const unsigned short* __restrict__ tblb,
    const int* __restrict__ pos_src, const int* __restrict__ pos_dst,
    const int* __restrict__ neg_src, const int* __restrict__ neg_dst,
    const float* __restrict__ b1, const float* __restrict__ W2,
    const float* __restrict__ b2,
    const unsigned short* __restrict__ w1t,
    float* __restrict__ out) {

    __shared__ __align__(16) unsigned short Bs[64 * 512];

    const int tid = threadIdx.x;
    const int l = tid & 63;
    const int wv = tid >> 6;
    const int l15 = l & 15;
    const int lq = l >> 4;
    const int m0 = blockIdx.x * 128;
    const bool is_pos = (m0 < E_EDGES);

    int nsrc[2], ndst[2];
#pragma unroll
    for (int mt = 0; mt < 2; ++mt) {
        int m = m0 + wv * 32 + mt * 16 + l15;
        if (is_pos) { nsrc[mt] = pos_src[m];            ndst[mt] = pos_dst[m]; }
        else        { int mm = m - E_EDGES; nsrc[mt] = neg_src[mm]; ndst[mt] = neg_dst[mm]; }
    }

    auto stageB = [&](int c) {
#pragma unroll
        for (int i = 0; i < 16; ++i) {
            int lc = wv * 16 + i;
            int gc = c * 64 + lc;
            const unsigned short* g = w1t + (size_t)gc * KDIM + ((l ^ i) << 3);
            char* lp = (char*)Bs + lc * 1024;
            __builtin_amdgcn_global_load_lds(
                (const __attribute__((address_space(1))) void*)g,
                (__attribute__((address_space(3))) void*)lp, 16, 0, 0);
        }
    };

    stageB(0);
    __builtin_amdgcn_sched_barrier(0);

    short8 af[2][16];
#pragma unroll
    for (int h = 0; h < 16; ++h)
#pragma unroll
        for (int mt = 0; mt < 2; ++mt) {
            int node = (h < 8) ? nsrc[mt] : ndst[mt];
            const unsigned short* g = tblb + (size_t)node * DFEAT + (h & 7) * 32 + lq * 8;
            af[mt][h] = *(const short8*)g;
        }
    __builtin_amdgcn_sched_barrier(0);

    f32x4 acc[2][4];
#pragma unroll
    for (int mt = 0; mt < 2; ++mt)
#pragma unroll
        for (int j = 0; j < 4; ++j)
            acc[mt][j] = (f32x4){0.f, 0.f, 0.f, 0.f};
    float rowacc[2][4] = {{0.f, 0.f, 0.f, 0.f}, {0.f, 0.f, 0.f, 0.f}};

    const char* Bb = (const char*)Bs;

#pragma unroll
    for (int c = 0; c < 4; ++c) {
        if (c == 0) {
            asm volatile("s_waitcnt vmcnt(32)" ::: "memory");
        } else {
            __syncthreads();
            stageB(c);
#pragma unroll
            for (int mt = 0; mt < 2; ++mt)
#pragma unroll
                for (int j = 0; j < 4; ++j) {
                    int col = (c - 1) * 64 + j * 16 + l15;
                    float b1v = b1[col], w2v = W2[col];
#pragma unroll
                    for (int r = 0; r < 4; ++r) {
                        float hv = fmaxf(acc[mt][j][r] + b1v, 0.f);
                        rowacc[mt][r] = fmaf(hv, w2v, rowacc[mt][r]);
                    }
                    acc[mt][j] = (f32x4){0.f, 0.f, 0.f, 0.f};
                }
            asm volatile("s_waitcnt vmcnt(0)" ::: "memory");
        }
        __builtin_amdgcn_s_barrier();

        __builtin_amdgcn_s_setprio(1);
#pragma unroll
        for (int h = 0; h < 16; ++h) {
            short8 bf[4];
#pragma unroll
            for (int j = 0; j < 4; ++j) {
                int cl = j * 16 + l15;
                int phys = (h * 4 + lq) ^ l15;
                bf[j] = *(const short8*)(Bb + cl * 1024 + phys * 16);
            }
#pragma unroll
            for (int mt = 0; mt < 2; ++mt)
#pragma unroll
                for (int j = 0; j < 4; ++j)
                    acc[mt][j] = __builtin_amdgcn_mfma_f32_16x16x32_bf16(af[mt][h], bf[j], acc[mt][j], 0, 0, 0);
        }
        __builtin_amdgcn_s_setprio(0);
    }

#pragma unroll
    for (int mt = 0; mt < 2; ++mt)
#pragma unroll
        for (int j = 0; j < 4; ++j) {
            int col = 3 * 64 + j * 16 + l15;
            float b1v = b1[col], w2v = W2[col];
#pragma unroll
            for (int r = 0; r < 4; ++r) {
                float hv = fmaxf(acc[mt][j][r] + b1v, 0.f);
                rowacc[mt][r] = fmaf(hv, w2v, rowacc[mt][r]);
            }
        }

    const float b2v = b2[0];
#pragma unroll
    for (int mt = 0; mt < 2; ++mt)
#pragma unroll
        for (int r = 0; r < 4; ++r) {
            float p = rowacc[mt][r];
#pragma unroll
            for (int mk = 1; mk < 16; mk <<= 1) p += __shfl_xor(p, mk, 64);
            if (l15 == 0) {
                int m = m0 + wv * 32 + mt * 16 + lq * 4 + r;
                float sg = 1.0f / (1.0f + __expf(-(p + b2v)));
                out[(size_t)m] = sg;
                out[(size_t)(2 * E_EDGES) + m] = is_pos ? 1.0f : 0.0f;
            }
        }
}

// ===================== fallback (round-1) =====================
__global__ __launch_bounds__(256) void linkpred_fb_kernel(
    const float* __restrict__ table,
    const int* __restrict__ pos_src, const int* __restrict__ pos_dst,
    const int* __restrict__ neg_src, const int* __restrict__ neg_dst,
    const float* __restrict__ b1, const float* __restrict__ W2,
    const float* __restrict__ b2,
    const unsigned short* __restrict__ w1t,
    float* __restrict__ out) {

    __shared__ __align__(16) unsigned short As[2][64 * 64];
    __shared__ int sIdx[64], dIdx[64];
    __shared__ float wpart[4][64];

    const int tid = threadIdx.x;
    const int l = tid & 63;
    const int wv = tid >> 6;
    const int m0 = blockIdx.x * 64;

    if (tid < 64) {
        int m = m0 + tid;
        int si, di;
        if (m < E_EDGES) { si = pos_src[m];            di = pos_dst[m]; }
        else             { si = neg_src[m - E_EDGES];  di = neg_dst[m - E_EDGES]; }
        sIdx[tid] = si;
        dIdx[tid] = di;
    }

    float b1v[4], w2v[4];
#pragma unroll
    for (int j = 0; j < 4; j++) {
        int n = wv * 64 + j * 16 + (l & 15);
        b1v[j] = b1[n];
        w2v[j] = W2[n];
    }

    __syncthreads();

    const int e0 = tid >> 3;
    const int q  = tid & 7;
    const int e1 = e0 + 32;

    auto pack_write = [&](int buf, int e, const float4& x, const float4& y) {
        uint4 w;
        w.x = (unsigned)f2bf(x.x) | ((unsigned)f2bf(x.y) << 16);
        w.y = (unsigned)f2bf(x.z) | ((unsigned)f2bf(x.w) << 16);
        w.z = (unsigned)f2bf(y.x) | ((unsigned)f2bf(y.y) << 16);
        w.w = (unsigned)f2bf(y.z) | ((unsigned)f2bf(y.w) << 16);
        int byte = e * 128 + q * 16;
        byte ^= (e & 7) << 4;
        *(uint4*)((char*)(&As[buf][0]) + byte) = w;
    };

    {
        const float* p0 = table + (size_t)sIdx[e0] * DFEAT + q * 8;
        const float* p1 = table + (size_t)sIdx[e1] * DFEAT + q * 8;
        float4 a0 = *(const float4*)p0, a1 = *(const float4*)(p0 + 4);
        float4 c0 = *(const float4*)p1, c1 = *(const float4*)(p1 + 4);
        pack_write(0, e0, a0, a1);
        pack_write(0, e1, c0, c1);
    }
    __syncthreads();

    f32x4 acc[4][4];
#pragma unroll
    for (int i = 0; i < 4; i++)
#pragma unroll
        for (int j = 0; j < 4; j++)
            acc[i][j] = (f32x4){0.f, 0.f, 0.f, 0.f};

    for (int s = 0; s < 8; s++) {
        float4 a0, a1, c0, c1;
        if (s < 7) {
            int sn = s + 1;
            const int* idxA = (sn < 4) ? sIdx : dIdx;
            int cb = (sn & 3) * 64 + q * 8;
            const float* p0 = table + (size_t)idxA[e0] * DFEAT + cb;
            const float* p1 = table + (size_t)idxA[e1] * DFEAT + cb;
            a0 = *(const float4*)p0; a1 = *(const float4*)(p0 + 4);
            c0 = *(const float4*)p1; c1 = *(const float4*)(p1 + 4);
        }

        const int cur = s & 1;
        const char* Abase = (const char*)(&As[cur][0]);
#pragma unroll
        for (int h = 0; h < 2; h++) {
            short8 af[4], bf[4];
#pragma unroll
            for (int i = 0; i < 4; i++) {
                int row = i * 16 + (l & 15);
                int byte = row * 128 + h * 64 + ((l >> 4) << 4);
                byte ^= (l & 7) << 4;
                af[i] = *(const short8*)(Abase + byte);
            }
#pragma unroll
            for (int j = 0; j < 4; j++) {
                int col = wv * 64 + j * 16 + (l & 15);
                int koff = s * 64 + h * 32 + ((l >> 4) << 3);
                bf[j] = *(const short8*)(w1t + col * KDIM + koff);
            }
#pragma unroll
            for (int i = 0; i < 4; i++)
#pragma unroll
                for (int j = 0; j < 4; j++)
                    acc[i][j] = __builtin_amdgcn_mfma_f32_16x16x32_bf16(af[i], bf[j], acc[i][j], 0, 0, 0);
        }

        if (s < 7) {
            pack_write((s + 1) & 1, e0, a0, a1);
            pack_write((s + 1) & 1, e1, c0, c1);
        }
        __syncthreads();
    }

    float part[16];
#pragma unroll
    for (int i = 0; i < 4; i++) {
#pragma unroll
        for (int r = 0; r < 4; r++) {
            float p = 0.f;
#pragma unroll
            for (int j = 0; j < 4; j++) {
                float hv = acc[i][j][r] + b1v[j];
                hv = fmaxf(hv, 0.f);
                p = fmaf(hv, w2v[j], p);
            }
#pragma unroll
            for (int mk = 1; mk < 16; mk <<= 1) p += __shfl_xor(p, mk, 64);
            part[i * 4 + r] = p;
        }
    }
    if ((l & 15) == 0) {
        int g = l >> 4;
#pragma unroll
        for (int i = 0; i < 4; i++)
#pragma unroll
            for (int r = 0; r < 4; r++)
                wpart[wv][i * 16 + g * 4 + r] = part[i * 4 + r];
    }
    __syncthreads();

    if (tid < 64) {
        float x = wpart[0][tid] + wpart[1][tid] + wpart[2][tid] + wpart[3][tid] + b2[0];
        float sg = 1.0f / (1.0f + __expf(-x));
        out[(size_t)m0 + tid] = sg;
        out[(size_t)(2 * E_EDGES) + m0 + tid] = (m0 < E_EDGES) ? 1.0f : 0.0f;
    }
}

extern "C" void kernel_launch(void* const* d_in, const int* in_sizes, int n_in,
                              void* d_out, int out_size, void* d_ws, size_t ws_size,
                              hipStream_t stream) {
    const float* table = (const float*)d_in[0];
    const int* ps = (const int*)d_in[1];
    const int* pd = (const int*)d_in[2];
    const int* ns = (const int*)d_in[3];
    const int* nd = (const int*)d_in[4];
    const float* W1 = (const float*)d_in[5];
    const float* b1 = (const float*)d_in[6];
    const float* W2 = (const float*)d_in[7];
    const float* b2 = (const float*)d_in[8];
    float* out = (float*)d_out;

    const size_t wB_bytes  = (size_t)KDIM * 256 * 2;           // 262,144
    const size_t uv_bytes  = (size_t)NNODES * KDIM * 2;        // 134,217,728
    const size_t tbl_bytes = (size_t)NNODES * DFEAT * 2;       // 67,108,864
    const size_t w1t_bytes = (size_t)256 * KDIM * 2;           // 262,144

    if (ws_size >= wB_bytes + uv_bytes) {
        unsigned short* wB = (unsigned short*)d_ws;
        unsigned short* uv = (unsigned short*)((char*)d_ws + wB_bytes);
        hipLaunchKernelGGL(prep_wB_kernel, dim3(512), dim3(256), 0, stream, W1, wB);
        hipLaunchKernelGGL(gemm_uv_kernel, dim3(2048), dim3(256), 0, stream, table, wB, uv);
        hipLaunchKernelGGL(edge_kernel, dim3(65536), dim3(256), 0, stream,
                           uv, ps, pd, ns, nd, b1, W2, b2, out);
    } else if (ws_size >= tbl_bytes + w1t_bytes) {
        unsigned short* tblb = (unsigned short*)d_ws;
        unsigned short* w1t = (unsigned short*)((char*)d_ws + tbl_bytes);
        hipLaunchKernelGGL(conv_table_kernel, dim3(16384), dim3(256), 0, stream, table, tblb);
        hipLaunchKernelGGL(prep_w1t_kernel, dim3(512), dim3(256), 0, stream, W1, w1t);
        hipLaunchKernelGGL(linkpred4_kernel, dim3(4096), dim3(256), 0, stream,
                           tblb, ps, pd, ns, nd, b1, W2, b2, w1t, out);
    } else {
        unsigned short* w1t = (unsigned short*)d_ws;
        hipLaunchKernelGGL(prep_w1t_kernel, dim3(512), dim3(256), 0, stream, W1, w1t);
        hipLaunchKernelGGL(linkpred_fb_kernel, dim3(8192), dim3(256), 0, stream,
                           table, ps, pd, ns, nd, b1, W2, b2, w1t, out);
    }
}